// Round 9
// baseline (264.724 us; speedup 1.0000x reference)
//
#include <hip/hip_runtime.h>

#define N_NODES   100000
#define N_EDGES   1600000
#define BSHIFT    9
#define NB        196        // ceil(100000 / 512)
#define BSTRIDE   9216       // per-bucket capacity: mean 8192, +11 sigma margin

typedef __attribute__((ext_vector_type(8))) short short8;
typedef __attribute__((ext_vector_type(4))) float f32x4;
typedef __attribute__((ext_vector_type(2))) float f32x2;

__device__ __forceinline__ unsigned short f2bf(float f) {
    unsigned u = __float_as_uint(f);
    u += 0x7FFF + ((u >> 16) & 1);          // round-to-nearest-even
    return (unsigned short)(u >> 16);
}

__device__ __forceinline__ int load_src(const int* e, int is64, int i) {
    return is64 ? e[2 * i] : e[i];
}
__device__ __forceinline__ int load_dst(const int* e, int is64, int i) {
    return is64 ? e[2 * (N_EDGES + i)] : e[N_EDGES + i];
}

// In-block edge-width self-detect: for int64 data all odd 32-bit words of the
// first 1024 entries are 0; for int32 they're random indices.
__device__ __forceinline__ int block_detect_is64(const int* e, int* s_nz) {
    if (threadIdx.x == 0) *s_nz = 0;
    __syncthreads();
    int v = 0;
    for (int i = threadIdx.x; i < 1024; i += 256) v |= e[2 * i + 1];
    if (v) atomicOr(s_nz, 1);
    __syncthreads();
    return (*s_nz == 0) ? 1 : 0;
}

// ---------------- phase A: single-pass bucket-binning + bf16/fp8 prep ------
// pairs entry: src (17 bits) | local-dst (9 bits) << 17.
__global__ __launch_bounds__(256) void phaseA_kernel(
        const int* __restrict__ e, const float* __restrict__ x,
        const float* __restrict__ W1_l, const float* __restrict__ W1_r,
        const float* __restrict__ W2_l, const float* __restrict__ W2_r,
        int* __restrict__ bktcur, int* __restrict__ pairs,
        short* __restrict__ xb, unsigned int* __restrict__ xq,
        short* __restrict__ W1t, short* __restrict__ W2lt, short* __restrict__ W2rt) {
    __shared__ int2 s_pairs[4096];
    __shared__ int s_cnt[256], s_off[256], s_base[256], s_cur[256];
    __shared__ int s_nz;
    const int blk = blockIdx.x;
    if (blk < 391) {
        const int tid = threadIdx.x;
        s_cnt[tid] = 0;
        int is64 = block_detect_is64(e, &s_nz);   // includes the needed barrier
        __syncthreads();
        int i0 = blk * 4096;
        int n = min(4096, N_EDGES - i0);
        int ls[16], ld[16];
        #pragma unroll
        for (int t = 0; t < 16; t++) {
            int k = t * 256 + tid;
            if (k < n) {
                ls[t] = load_src(e, is64, i0 + k);
                ld[t] = load_dst(e, is64, i0 + k);
                atomicAdd(&s_cnt[ld[t] >> BSHIFT], 1);
            }
        }
        __syncthreads();
        int lv = s_cnt[tid];
        s_off[tid] = lv;
        __syncthreads();
        for (int off = 1; off < 256; off <<= 1) {
            int t = (tid >= off) ? s_off[tid - off] : 0;
            __syncthreads();
            s_off[tid] += t;
            __syncthreads();
        }
        int excl = s_off[tid] - lv;
        int gb = 0;
        if (tid < NB && lv > 0) gb = atomicAdd(&bktcur[tid], lv);
        s_off[tid] = excl;
        s_base[tid] = tid * BSTRIDE + gb;
        s_cur[tid] = excl;
        __syncthreads();
        #pragma unroll
        for (int t = 0; t < 16; t++) {
            int k = t * 256 + tid;
            if (k < n) {
                int pos = atomicAdd(&s_cur[ld[t] >> BSHIFT], 1);
                s_pairs[pos] = (int2){ls[t], ld[t]};
            }
        }
        __syncthreads();
        for (int j = tid; j < n; j += 256) {
            int2 pr = s_pairs[j];
            int b = pr.y >> BSHIFT;
            pairs[s_base[b] + (j - s_off[b])] = pr.x | ((pr.y & 511) << 17);
        }
    } else if (blk < 6641) {
        int t = (blk - 391) * 256 + threadIdx.x;
        size_t i = (size_t)t * 8;
        float4 v0 = *(const float4*)&x[i];
        float4 v1 = *(const float4*)&x[i + 4];
        short8 o;
        o[0] = (short)f2bf(v0.x); o[1] = (short)f2bf(v0.y);
        o[2] = (short)f2bf(v0.z); o[3] = (short)f2bf(v0.w);
        o[4] = (short)f2bf(v1.x); o[5] = (short)f2bf(v1.y);
        o[6] = (short)f2bf(v1.z); o[7] = (short)f2bf(v1.w);
        *(short8*)&xb[i] = o;
        int w0 = __builtin_amdgcn_cvt_pk_fp8_f32(v0.x, v0.y, 0, false);
        w0 = __builtin_amdgcn_cvt_pk_fp8_f32(v0.z, v0.w, w0, true);
        int w1 = __builtin_amdgcn_cvt_pk_fp8_f32(v1.x, v1.y, 0, false);
        w1 = __builtin_amdgcn_cvt_pk_fp8_f32(v1.z, v1.w, w1, true);
        uint2 wq; wq.x = (unsigned int)w0; wq.y = (unsigned int)w1;
        *(uint2*)&xq[t * 2] = wq;
    } else {
        int i = (blk - 6641) * 256 + threadIdx.x;
        if (i < 32768) {
            int n = i >> 8, k = i & 255;
            float v = (k < 128) ? W1_l[k * 128 + n] : W1_r[(k - 128) * 128 + n];
            W1t[i] = (short)f2bf(v);
        } else if (i < 40960) {
            int j = i - 32768, n = j >> 7, k = j & 127;
            W2lt[j] = (short)f2bf(W2_l[k * 64 + n]);
        } else {
            int j = i - 40960, n = j >> 7, k = j & 127;
            W2rt[j] = (short)f2bf(W2_r[k * 64 + n]);
        }
    }
}

// ---------------- fused CSR tail (fixed-stride buckets, 512 thr/node) ------
__global__ __launch_bounds__(512) void fused_fill_kernel(
        const int* __restrict__ bktcur, const int* __restrict__ pairs,
        int* __restrict__ deg_i, int* __restrict__ cursor,
        float* __restrict__ inv_deg, int* __restrict__ col) {
    __shared__ int ldeg[512];
    __shared__ int ssum[512];
    const int tid = threadIdx.x;
    const int b = blockIdx.x;
    const int nbase = b << BSHIFT;
    ldeg[tid] = 0;
    __syncthreads();
    const int cnt = bktcur[b];
    const int p0 = b * BSTRIDE;
    for (int j = tid; j < cnt; j += 512)
        atomicAdd(&ldeg[pairs[p0 + j] >> 17], 1);
    __syncthreads();
    int d = ldeg[tid];
    ssum[tid] = d;
    __syncthreads();
    for (int off = 1; off < 512; off <<= 1) {
        int t = (tid >= off) ? ssum[tid - off] : 0;
        __syncthreads();
        ssum[tid] += t;
        __syncthreads();
    }
    int s = p0 + ssum[tid] - d;          // row start for node nbase+tid
    int node = nbase + tid;
    if (node < N_NODES) {
        deg_i[node] = d;
        cursor[node] = s;
        inv_deg[node] = 1.0f / fmaxf((float)d, 1.0f);
    }
    ldeg[tid] = s;                        // becomes scatter cursor
    __syncthreads();
    for (int j = tid; j < cnt; j += 512) {
        int pk = pairs[p0 + j];
        int pos = atomicAdd(&ldeg[pk >> 17], 1);
        col[pos] = pk & 0x1FFFF;
    }
}

// ---------------- fp8 helpers ----------------
__device__ __forceinline__ void acc_fp8x8(float* acc, uint2 w) {
    f32x2 f;
    f = __builtin_amdgcn_cvt_pk_f32_fp8((int)w.x, false); acc[0] += f[0]; acc[1] += f[1];
    f = __builtin_amdgcn_cvt_pk_f32_fp8((int)w.x, true);  acc[2] += f[0]; acc[3] += f[1];
    f = __builtin_amdgcn_cvt_pk_f32_fp8((int)w.y, false); acc[4] += f[0]; acc[5] += f[1];
    f = __builtin_amdgcn_cvt_pk_f32_fp8((int)w.y, true);  acc[6] += f[0]; acc[7] += f[1];
}

// layer-1 aggregation: fp8 rows (128 B), 16 lanes x 8 B per node.
// Narrow requests maximize outstanding-request count; 8-deep unroll.
__global__ __launch_bounds__(256) void agg128_kernel(
        const int* __restrict__ cursor, const int* __restrict__ deg_i,
        const int* __restrict__ col, const unsigned int* __restrict__ xq,
        const float* __restrict__ inv_deg, short* __restrict__ agg) {
    int node = blockIdx.x * 16 + (threadIdx.x >> 4);
    int lane = threadIdx.x & 15;
    int cnt = deg_i[node];
    int start = cursor[node];
    float acc[8] = {0.f};
    int k = 0;
    for (; k + 8 <= cnt; k += 8) {
        int s[8];
        #pragma unroll
        for (int j = 0; j < 8; j++) s[j] = col[start + k + j];
        uint2 w[8];
        #pragma unroll
        for (int j = 0; j < 8; j++)
            w[j] = *(const uint2*)(xq + (size_t)s[j] * 32 + lane * 2);
        #pragma unroll
        for (int j = 0; j < 8; j++) acc_fp8x8(acc, w[j]);
    }
    for (; k < cnt; k++) {
        uint2 w = *(const uint2*)(xq + (size_t)col[start + k] * 32 + lane * 2);
        acc_fp8x8(acc, w);
    }
    float sc = inv_deg[node];
    short8 o;
    #pragma unroll
    for (int j = 0; j < 8; j++) o[j] = (short)f2bf(acc[j] * sc);
    *(short8*)(agg + (size_t)node * 128 + lane * 8) = o;
}

// layer-2 aggregation: fp8 p rows (64 B), 8 lanes x 8 B per node; RMW on
// out with the read issued BEFORE the gather (latency hides under it).
__global__ __launch_bounds__(256) void agg64_kernel(
        const int* __restrict__ cursor, const int* __restrict__ deg_i,
        const int* __restrict__ col, const unsigned int* __restrict__ pq,
        const float* __restrict__ inv_deg, float* __restrict__ out) {
    int node = blockIdx.x * 32 + (threadIdx.x >> 3);
    int lane = threadIdx.x & 7;
    int cnt = deg_i[node];
    int start = cursor[node];
    float sc = inv_deg[node];
    float* dst = out + (size_t)node * 64 + lane * 8;
    float4 r0 = *(float4*)dst;            // issue RMW reads early
    float4 r1 = *(float4*)(dst + 4);
    float acc[8] = {0.f};
    int k = 0;
    for (; k + 8 <= cnt; k += 8) {
        int s[8];
        #pragma unroll
        for (int j = 0; j < 8; j++) s[j] = col[start + k + j];
        uint2 w[8];
        #pragma unroll
        for (int j = 0; j < 8; j++)
            w[j] = *(const uint2*)(pq + (size_t)s[j] * 16 + lane * 2);
        #pragma unroll
        for (int j = 0; j < 8; j++) acc_fp8x8(acc, w[j]);
    }
    for (; k < cnt; k++) {
        uint2 w = *(const uint2*)(pq + (size_t)col[start + k] * 16 + lane * 2);
        acc_fp8x8(acc, w);
    }
    r0.x += acc[0] * sc; r0.y += acc[1] * sc; r0.z += acc[2] * sc; r0.w += acc[3] * sc;
    r1.x += acc[4] * sc; r1.y += acc[5] * sc; r1.z += acc[6] * sc; r1.w += acc[7] * sc;
    *(float4*)dst = r0;
    *(float4*)(dst + 4) = r1;
}

// ---------------- one-shot fused MFMA: h = relu(A@W1+b1) in LDS,
// then p8 = fp8(h@W2_l), out = h@W2_r + b2 — h never touches global.
// 3125 blocks (12.2/CU queued), __launch_bounds__(256,2) keeps the
// R3-measured VGPR-116 codegen; block-level TLP replaces the persistent
// loop whose per-iteration barrier drained all prefetches (vmcnt(0)).
__global__ __launch_bounds__(256, 2) void gemm12_mfma(
        const short* __restrict__ agg1, const short* __restrict__ xb,
        const short* __restrict__ W1t, const float* __restrict__ b1,
        const short* __restrict__ W2lt, const short* __restrict__ W2rt,
        const float* __restrict__ b2,
        unsigned char* __restrict__ p8, float* __restrict__ out) {
    __shared__ __align__(16) char hsb[8192];     // 32 rows x 256 B, XOR-swizzled
    const int wave = threadIdx.x >> 6, lane = threadIdx.x & 63;
    const int m = lane & 15, q = lane >> 4;
    const int P = blockIdx.x;                    // rows 32P .. 32P+32

    // A loads issued first (HBM/L3); weight loads (L2-hit, shared addrs) follow
    short8 a[2][8];
    #pragma unroll
    for (int tt = 0; tt < 2; tt++) {
        const short* arow = agg1 + (size_t)((2 * P + tt) * 16 + m) * 128;
        const short* xrow = xb   + (size_t)((2 * P + tt) * 16 + m) * 128;
        #pragma unroll
        for (int c = 0; c < 4; c++) {
            a[tt][c]     = *(const short8*)(arow + c * 32 + q * 8);
            a[tt][c + 4] = *(const short8*)(xrow + c * 32 + q * 8);
        }
    }
    // phase-1 W1 fragments: this wave's 32 h-cols [wave*32, wave*32+32)
    short8 breg[2][8];
    #pragma unroll
    for (int t = 0; t < 2; t++)
        #pragma unroll
        for (int c = 0; c < 8; c++)
            breg[t][c] = *(const short8*)(W1t + (size_t)(wave * 32 + t * 16 + m) * 256 + c * 32 + q * 8);
    float bias1[2];
    bias1[0] = b1[wave * 32 + m];
    bias1[1] = b1[wave * 32 + 16 + m];

    // phase-2 fragments: waves 0,1 -> p cols [pw*32,+32); waves 2,3 -> out cols
    const int pw = wave & 1;
    const short* Wp = (wave < 2) ? W2lt : W2rt;
    short8 w2[2][4];
    #pragma unroll
    for (int t = 0; t < 2; t++)
        #pragma unroll
        for (int c = 0; c < 4; c++)
            w2[t][c] = *(const short8*)(Wp + (size_t)(pw * 32 + t * 16 + m) * 128 + c * 32 + q * 8);
    float bias2[2];
    bias2[0] = b2[pw * 32 + m];
    bias2[1] = b2[pw * 32 + 16 + m];

    const int wb = wave * 64 + m * 2;        // phase-1 write col byte base
    const int rsw = (m & 7) << 4;            // phase-2 read swizzle

    // ---- phase 1: h = relu(A @ W1 + b1), 2 tiles x this wave's 32 cols
    f32x4 acc[2][2];
    #pragma unroll
    for (int tt = 0; tt < 2; tt++)
        #pragma unroll
        for (int t = 0; t < 2; t++) acc[tt][t] = (f32x4){0.f, 0.f, 0.f, 0.f};
    #pragma unroll
    for (int c = 0; c < 8; c++)
        #pragma unroll
        for (int tt = 0; tt < 2; tt++)
            #pragma unroll
            for (int t = 0; t < 2; t++)
                acc[tt][t] = __builtin_amdgcn_mfma_f32_16x16x32_bf16(a[tt][c], breg[t][c], acc[tt][t], 0, 0, 0);
    // write h tile to swizzled LDS
    #pragma unroll
    for (int tt = 0; tt < 2; tt++)
        #pragma unroll
        for (int t = 0; t < 2; t++)
            #pragma unroll
            for (int r = 0; r < 4; r++) {
                int row = tt * 16 + q * 4 + r;
                int byteoff = row * 256 + ((wb + t * 32) ^ ((row & 7) << 4));
                float v = fmaxf(acc[tt][t][r] + bias1[t], 0.f);
                *(short*)(hsb + byteoff) = (short)f2bf(v);
            }
    __syncthreads();
    // ---- phase 2: p = h@W2_l (waves 0,1), o = h@W2_r + b2 (waves 2,3)
    f32x4 acc2[2][2];
    #pragma unroll
    for (int tt = 0; tt < 2; tt++) {
        short8 a2[4];
        int rowbyte = (tt * 16 + m) * 256;
        #pragma unroll
        for (int c = 0; c < 4; c++)
            a2[c] = *(const short8*)(hsb + rowbyte + ((q * 16 + c * 64) ^ rsw));
        #pragma unroll
        for (int t = 0; t < 2; t++) acc2[tt][t] = (f32x4){0.f, 0.f, 0.f, 0.f};
        #pragma unroll
        for (int c = 0; c < 4; c++)
            #pragma unroll
            for (int t = 0; t < 2; t++)
                acc2[tt][t] = __builtin_amdgcn_mfma_f32_16x16x32_bf16(a2[c], w2[t][c], acc2[tt][t], 0, 0, 0);
    }
    if (wave < 2) {
        #pragma unroll
        for (int tt = 0; tt < 2; tt++)
            #pragma unroll
            for (int t = 0; t < 2; t++) {
                int colc = pw * 32 + t * 16 + m;
                #pragma unroll
                for (int r = 0; r < 4; r++) {
                    int rr = (2 * P + tt) * 16 + q * 4 + r;
                    float pv = acc2[tt][t][r];
                    int w8 = __builtin_amdgcn_cvt_pk_fp8_f32(pv, pv, 0, false);
                    p8[(size_t)rr * 64 + colc] = (unsigned char)(w8 & 0xFF);
                }
            }
    } else {
        #pragma unroll
        for (int tt = 0; tt < 2; tt++)
            #pragma unroll
            for (int t = 0; t < 2; t++) {
                int colc = pw * 32 + t * 16 + m;
                #pragma unroll
                for (int r = 0; r < 4; r++) {
                    int rr = (2 * P + tt) * 16 + q * 4 + r;
                    out[(size_t)rr * 64 + colc] = acc2[tt][t][r] + bias2[t];
                }
            }
    }
}

extern "C" void kernel_launch(void* const* d_in, const int* in_sizes, int n_in,
                              void* d_out, int out_size, void* d_ws, size_t ws_size,
                              hipStream_t stream) {
    const float* x    = (const float*)d_in[0];
    const int*   edge = (const int*)d_in[1];
    const float* W1_l = (const float*)d_in[2];
    const float* b1   = (const float*)d_in[3];
    const float* W1_r = (const float*)d_in[4];
    const float* W2_l = (const float*)d_in[5];
    const float* b2   = (const float*)d_in[6];
    const float* W2_r = (const float*)d_in[7];
    float* out = (float*)d_out;

    // ---- workspace layout (~86 MB) ----
    int* iw = (int*)d_ws;
    int* deg_i  = iw;                        // 100000
    int* cursor = iw + 100000;               // 100000 (row starts)
    int* bktcur = iw + 200000;               // 256 bucket cursors (zeroed below)
    float* inv_deg = (float*)(iw + 200256);  // 100096
    int* col    = iw + 300352;               // 196*9216 = 1806336 (gapped CSR)
    short* xb   = (short*)(iw + 2106688);    // 12.8M bf16
    short* hb   = xb + 12800000;             // 12.8M region: xq then p8/pq
    short* ag1  = hb + 12800000;             // 12.8M bf16 (layer-1 agg)
    short* W1t  = ag1 + 12800000;            // 32768
    short* W2lt = W1t + 32768;               // 8192
    short* W2rt = W2lt + 8192;               // 8192
    unsigned int* xq = (unsigned int*)hb;    // phaseA writes, agg128 reads, then dead
    int* pairs = (int*)ag1;                  // overlay: consumed by fill before agg128 writes ag1
    unsigned char* p8 = (unsigned char*)hb;  // overlay: xq dead after agg128
    unsigned int*  pq = (unsigned int*)hb;

    hipMemsetAsync(bktcur, 0, 256 * sizeof(int), stream);

    // phase A: single-pass bucket binning + bf16/fp8 prep, one grid
    phaseA_kernel<<<6833, 256, 0, stream>>>(edge, x, W1_l, W1_r, W2_l, W2_r,
                                            bktcur, pairs, xb, xq, W1t, W2lt, W2rt);
    // CSR build (per-bucket, fixed stride, one thread per node)
    fused_fill_kernel<<<NB, 512, 0, stream>>>(bktcur, pairs, deg_i, cursor, inv_deg, col);

    // layer 1 aggregation (16 lanes/node, 8-deep unroll)
    agg128_kernel<<<6250, 256, 0, stream>>>(cursor, deg_i, col, xq, inv_deg, ag1);
    // fused layer-1 GEMM + layer-2 projection (one-shot, block-level TLP)
    gemm12_mfma<<<3125, 256, 0, stream>>>(ag1, xb, W1t, b1, W2lt, W2rt, b2, p8, out);
    // layer 2 aggregation (RMW on out, early RMW-read, 8-deep unroll)
    agg64_kernel<<<3125, 256, 0, stream>>>(cursor, deg_i, col, pq, inv_deg, out);
}

// Round 10
// 246.350 us; speedup vs baseline: 1.0746x; 1.0746x over previous
//
#include <hip/hip_runtime.h>

#define N_NODES   100000
#define N_EDGES   1600000
#define BSHIFT    9
#define NB        196        // ceil(100000 / 512)
#define BSTRIDE   9216       // per-bucket capacity: mean 8192, +11 sigma margin

typedef __attribute__((ext_vector_type(8))) short short8;
typedef __attribute__((ext_vector_type(4))) float f32x4;
typedef __attribute__((ext_vector_type(2))) float f32x2;

__device__ __forceinline__ unsigned short f2bf(float f) {
    unsigned u = __float_as_uint(f);
    u += 0x7FFF + ((u >> 16) & 1);          // round-to-nearest-even
    return (unsigned short)(u >> 16);
}

__device__ __forceinline__ int load_src(const int* e, int is64, int i) {
    return is64 ? e[2 * i] : e[i];
}
__device__ __forceinline__ int load_dst(const int* e, int is64, int i) {
    return is64 ? e[2 * (N_EDGES + i)] : e[N_EDGES + i];
}

// In-block edge-width self-detect: for int64 data all odd 32-bit words of the
// first 1024 entries are 0; for int32 they're random indices.
__device__ __forceinline__ int block_detect_is64(const int* e, int* s_nz) {
    if (threadIdx.x == 0) *s_nz = 0;
    __syncthreads();
    int v = 0;
    for (int i = threadIdx.x; i < 1024; i += 256) v |= e[2 * i + 1];
    if (v) atomicOr(s_nz, 1);
    __syncthreads();
    return (*s_nz == 0) ? 1 : 0;
}

// ---------------- phase A: single-pass bucket-binning + bf16/fp8 prep ------
// Binning split to 782 x 2048 edges (16 KB s_pairs): halves the per-block
// serial LDS-atomic/barrier work so the binning tail hides under the 6250
// streaming-conversion blocks.
// pairs entry: src (17 bits) | local-dst (9 bits) << 17.
__global__ __launch_bounds__(256) void phaseA_kernel(
        const int* __restrict__ e, const float* __restrict__ x,
        const float* __restrict__ W1_l, const float* __restrict__ W1_r,
        const float* __restrict__ W2_l, const float* __restrict__ W2_r,
        int* __restrict__ bktcur, int* __restrict__ pairs,
        short* __restrict__ xb, unsigned int* __restrict__ xq,
        short* __restrict__ W1t, short* __restrict__ W2lt, short* __restrict__ W2rt) {
    __shared__ int2 s_pairs[2048];
    __shared__ int s_cnt[256], s_off[256], s_base[256], s_cur[256];
    __shared__ int s_nz;
    const int blk = blockIdx.x;
    if (blk < 782) {
        const int tid = threadIdx.x;
        s_cnt[tid] = 0;
        int is64 = block_detect_is64(e, &s_nz);   // includes the needed barrier
        __syncthreads();
        int i0 = blk * 2048;
        int n = min(2048, N_EDGES - i0);
        int ls[8], ld[8];
        #pragma unroll
        for (int t = 0; t < 8; t++) {
            int k = t * 256 + tid;
            if (k < n) {
                ls[t] = load_src(e, is64, i0 + k);
                ld[t] = load_dst(e, is64, i0 + k);
                atomicAdd(&s_cnt[ld[t] >> BSHIFT], 1);
            }
        }
        __syncthreads();
        int lv = s_cnt[tid];
        s_off[tid] = lv;
        __syncthreads();
        for (int off = 1; off < 256; off <<= 1) {
            int t = (tid >= off) ? s_off[tid - off] : 0;
            __syncthreads();
            s_off[tid] += t;
            __syncthreads();
        }
        int excl = s_off[tid] - lv;
        int gb = 0;
        if (tid < NB && lv > 0) gb = atomicAdd(&bktcur[tid], lv);
        s_off[tid] = excl;
        s_base[tid] = tid * BSTRIDE + gb;
        s_cur[tid] = excl;
        __syncthreads();
        #pragma unroll
        for (int t = 0; t < 8; t++) {
            int k = t * 256 + tid;
            if (k < n) {
                int pos = atomicAdd(&s_cur[ld[t] >> BSHIFT], 1);
                s_pairs[pos] = (int2){ls[t], ld[t]};
            }
        }
        __syncthreads();
        for (int j = tid; j < n; j += 256) {
            int2 pr = s_pairs[j];
            int b = pr.y >> BSHIFT;
            pairs[s_base[b] + (j - s_off[b])] = pr.x | ((pr.y & 511) << 17);
        }
    } else if (blk < 7032) {
        int t = (blk - 782) * 256 + threadIdx.x;
        size_t i = (size_t)t * 8;
        float4 v0 = *(const float4*)&x[i];
        float4 v1 = *(const float4*)&x[i + 4];
        short8 o;
        o[0] = (short)f2bf(v0.x); o[1] = (short)f2bf(v0.y);
        o[2] = (short)f2bf(v0.z); o[3] = (short)f2bf(v0.w);
        o[4] = (short)f2bf(v1.x); o[5] = (short)f2bf(v1.y);
        o[6] = (short)f2bf(v1.z); o[7] = (short)f2bf(v1.w);
        *(short8*)&xb[i] = o;
        int w0 = __builtin_amdgcn_cvt_pk_fp8_f32(v0.x, v0.y, 0, false);
        w0 = __builtin_amdgcn_cvt_pk_fp8_f32(v0.z, v0.w, w0, true);
        int w1 = __builtin_amdgcn_cvt_pk_fp8_f32(v1.x, v1.y, 0, false);
        w1 = __builtin_amdgcn_cvt_pk_fp8_f32(v1.z, v1.w, w1, true);
        uint2 wq; wq.x = (unsigned int)w0; wq.y = (unsigned int)w1;
        *(uint2*)&xq[t * 2] = wq;
    } else {
        int i = (blk - 7032) * 256 + threadIdx.x;
        if (i < 32768) {
            int n = i >> 8, k = i & 255;
            float v = (k < 128) ? W1_l[k * 128 + n] : W1_r[(k - 128) * 128 + n];
            W1t[i] = (short)f2bf(v);
        } else if (i < 40960) {
            int j = i - 32768, n = j >> 7, k = j & 127;
            W2lt[j] = (short)f2bf(W2_l[k * 64 + n]);
        } else {
            int j = i - 40960, n = j >> 7, k = j & 127;
            W2rt[j] = (short)f2bf(W2_r[k * 64 + n]);
        }
    }
}

// ---------------- fused CSR tail (fixed-stride buckets, 512 thr/node) ------
__global__ __launch_bounds__(512) void fused_fill_kernel(
        const int* __restrict__ bktcur, const int* __restrict__ pairs,
        int* __restrict__ deg_i, int* __restrict__ cursor,
        float* __restrict__ inv_deg, int* __restrict__ col) {
    __shared__ int ldeg[512];
    __shared__ int ssum[512];
    const int tid = threadIdx.x;
    const int b = blockIdx.x;
    const int nbase = b << BSHIFT;
    ldeg[tid] = 0;
    __syncthreads();
    const int cnt = bktcur[b];
    const int p0 = b * BSTRIDE;
    for (int j = tid; j < cnt; j += 512)
        atomicAdd(&ldeg[pairs[p0 + j] >> 17], 1);
    __syncthreads();
    int d = ldeg[tid];
    ssum[tid] = d;
    __syncthreads();
    for (int off = 1; off < 512; off <<= 1) {
        int t = (tid >= off) ? ssum[tid - off] : 0;
        __syncthreads();
        ssum[tid] += t;
        __syncthreads();
    }
    int s = p0 + ssum[tid] - d;          // row start for node nbase+tid
    int node = nbase + tid;
    if (node < N_NODES) {
        deg_i[node] = d;
        cursor[node] = s;
        inv_deg[node] = 1.0f / fmaxf((float)d, 1.0f);
    }
    ldeg[tid] = s;                        // becomes scatter cursor
    __syncthreads();
    for (int j = tid; j < cnt; j += 512) {
        int pk = pairs[p0 + j];
        int pos = atomicAdd(&ldeg[pk >> 17], 1);
        col[pos] = pk & 0x1FFFF;
    }
}

// ---------------- fp8 helpers ----------------
__device__ __forceinline__ void acc_fp8x8(float* acc, uint2 w) {
    f32x2 f;
    f = __builtin_amdgcn_cvt_pk_f32_fp8((int)w.x, false); acc[0] += f[0]; acc[1] += f[1];
    f = __builtin_amdgcn_cvt_pk_f32_fp8((int)w.x, true);  acc[2] += f[0]; acc[3] += f[1];
    f = __builtin_amdgcn_cvt_pk_f32_fp8((int)w.y, false); acc[4] += f[0]; acc[5] += f[1];
    f = __builtin_amdgcn_cvt_pk_f32_fp8((int)w.y, true);  acc[6] += f[0]; acc[7] += f[1];
}

// layer-1 aggregation: fp8 rows (128 B), 16 lanes x 8 B per node.
// Narrow requests maximize outstanding-request count; 8-deep unroll.
__global__ __launch_bounds__(256) void agg128_kernel(
        const int* __restrict__ cursor, const int* __restrict__ deg_i,
        const int* __restrict__ col, const unsigned int* __restrict__ xq,
        const float* __restrict__ inv_deg, short* __restrict__ agg) {
    int node = blockIdx.x * 16 + (threadIdx.x >> 4);
    int lane = threadIdx.x & 15;
    int cnt = deg_i[node];
    int start = cursor[node];
    float acc[8] = {0.f};
    int k = 0;
    for (; k + 8 <= cnt; k += 8) {
        int s[8];
        #pragma unroll
        for (int j = 0; j < 8; j++) s[j] = col[start + k + j];
        uint2 w[8];
        #pragma unroll
        for (int j = 0; j < 8; j++)
            w[j] = *(const uint2*)(xq + (size_t)s[j] * 32 + lane * 2);
        #pragma unroll
        for (int j = 0; j < 8; j++) acc_fp8x8(acc, w[j]);
    }
    for (; k < cnt; k++) {
        uint2 w = *(const uint2*)(xq + (size_t)col[start + k] * 32 + lane * 2);
        acc_fp8x8(acc, w);
    }
    float sc = inv_deg[node];
    short8 o;
    #pragma unroll
    for (int j = 0; j < 8; j++) o[j] = (short)f2bf(acc[j] * sc);
    *(short8*)(agg + (size_t)node * 128 + lane * 8) = o;
}

// layer-2 aggregation: fp8 p rows (64 B), 8 lanes x 8 B per node; RMW on
// out with the read issued BEFORE the gather (latency hides under it).
__global__ __launch_bounds__(256) void agg64_kernel(
        const int* __restrict__ cursor, const int* __restrict__ deg_i,
        const int* __restrict__ col, const unsigned int* __restrict__ pq,
        const float* __restrict__ inv_deg, float* __restrict__ out) {
    int node = blockIdx.x * 32 + (threadIdx.x >> 3);
    int lane = threadIdx.x & 7;
    int cnt = deg_i[node];
    int start = cursor[node];
    float sc = inv_deg[node];
    float* dst = out + (size_t)node * 64 + lane * 8;
    float4 r0 = *(float4*)dst;            // issue RMW reads early
    float4 r1 = *(float4*)(dst + 4);
    float acc[8] = {0.f};
    int k = 0;
    for (; k + 8 <= cnt; k += 8) {
        int s[8];
        #pragma unroll
        for (int j = 0; j < 8; j++) s[j] = col[start + k + j];
        uint2 w[8];
        #pragma unroll
        for (int j = 0; j < 8; j++)
            w[j] = *(const uint2*)(pq + (size_t)s[j] * 16 + lane * 2);
        #pragma unroll
        for (int j = 0; j < 8; j++) acc_fp8x8(acc, w[j]);
    }
    for (; k < cnt; k++) {
        uint2 w = *(const uint2*)(pq + (size_t)col[start + k] * 16 + lane * 2);
        acc_fp8x8(acc, w);
    }
    r0.x += acc[0] * sc; r0.y += acc[1] * sc; r0.z += acc[2] * sc; r0.w += acc[3] * sc;
    r1.x += acc[4] * sc; r1.y += acc[5] * sc; r1.z += acc[6] * sc; r1.w += acc[7] * sc;
    *(float4*)dst = r0;
    *(float4*)(dst + 4) = r1;
}

// ---------------- fused persistent MFMA: h = relu(A@W1+b1) in LDS,
// then p8 = fp8(h@W2_l), out = h@W2_r + b2 — h never touches global.
// R3/R7-measured codegen (512 blocks, VGPR 116). Prefetch of the next
// pair's A is issued AFTER the barrier so the barrier's vmcnt(0) drain
// doesn't kill it; the loads fly over phase 2 and are consumed at the
// next loop top with no intervening barrier (hs[2] double buffer).
__global__ __launch_bounds__(256, 2) void gemm12_mfma(
        const short* __restrict__ agg1, const short* __restrict__ xb,
        const short* __restrict__ W1t, const float* __restrict__ b1,
        const short* __restrict__ W2lt, const short* __restrict__ W2rt,
        const float* __restrict__ b2,
        unsigned char* __restrict__ p8, float* __restrict__ out) {
    __shared__ __align__(16) char hs[2][8192];   // 2 x 32 rows x 256 B, XOR-swizzled
    const int wave = threadIdx.x >> 6, lane = threadIdx.x & 63;
    const int m = lane & 15, q = lane >> 4;

    // phase-1 W1 fragments: this wave's 32 h-cols [wave*32, wave*32+32)
    short8 breg[2][8];
    #pragma unroll
    for (int t = 0; t < 2; t++)
        #pragma unroll
        for (int c = 0; c < 8; c++)
            breg[t][c] = *(const short8*)(W1t + (size_t)(wave * 32 + t * 16 + m) * 256 + c * 32 + q * 8);
    float bias1[2];
    bias1[0] = b1[wave * 32 + m];
    bias1[1] = b1[wave * 32 + 16 + m];

    // phase-2 fragments: waves 0,1 -> p cols [pw*32,+32); waves 2,3 -> out cols
    const int pw = wave & 1;
    const short* Wp = (wave < 2) ? W2lt : W2rt;
    short8 w2[2][4];
    #pragma unroll
    for (int t = 0; t < 2; t++)
        #pragma unroll
        for (int c = 0; c < 4; c++)
            w2[t][c] = *(const short8*)(Wp + (size_t)(pw * 32 + t * 16 + m) * 128 + c * 32 + q * 8);
    float bias2[2];
    bias2[0] = b2[pw * 32 + m];
    bias2[1] = b2[pw * 32 + 16 + m];

    int P = blockIdx.x;                      // pair index: tiles 2P, 2P+1
    short8 a[2][8];
    #pragma unroll
    for (int tt = 0; tt < 2; tt++) {
        const short* arow = agg1 + (size_t)((2 * P + tt) * 16 + m) * 128;
        const short* xrow = xb   + (size_t)((2 * P + tt) * 16 + m) * 128;
        #pragma unroll
        for (int c = 0; c < 4; c++) {
            a[tt][c]     = *(const short8*)(arow + c * 32 + q * 8);
            a[tt][c + 4] = *(const short8*)(xrow + c * 32 + q * 8);
        }
    }
    const int wb = wave * 64 + m * 2;        // phase-1 write col byte base
    const int rsw = (m & 7) << 4;            // phase-2 read swizzle
    int buf = 0;
    while (true) {
        // ---- phase 1: h = relu(A @ W1 + b1), 2 tiles x this wave's 32 cols
        f32x4 acc[2][2];
        #pragma unroll
        for (int tt = 0; tt < 2; tt++)
            #pragma unroll
            for (int t = 0; t < 2; t++) acc[tt][t] = (f32x4){0.f, 0.f, 0.f, 0.f};
        #pragma unroll
        for (int c = 0; c < 8; c++)
            #pragma unroll
            for (int tt = 0; tt < 2; tt++)
                #pragma unroll
                for (int t = 0; t < 2; t++)
                    acc[tt][t] = __builtin_amdgcn_mfma_f32_16x16x32_bf16(a[tt][c], breg[t][c], acc[tt][t], 0, 0, 0);
        // write h tile to swizzled LDS
        char* hb0 = hs[buf];
        #pragma unroll
        for (int tt = 0; tt < 2; tt++)
            #pragma unroll
            for (int t = 0; t < 2; t++)
                #pragma unroll
                for (int r = 0; r < 4; r++) {
                    int row = tt * 16 + q * 4 + r;
                    int byteoff = row * 256 + ((wb + t * 32) ^ ((row & 7) << 4));
                    float v = fmaxf(acc[tt][t][r] + bias1[t], 0.f);
                    *(short*)(hb0 + byteoff) = (short)f2bf(v);
                }
        __syncthreads();
        // issue next pair's A-loads AFTER the barrier: they stay in flight
        // across phase 2 and are first used at the next loop top.
        int Pn = P + 512;
        if (Pn < 3125) {
            #pragma unroll
            for (int tt = 0; tt < 2; tt++) {
                const short* arow = agg1 + (size_t)((2 * Pn + tt) * 16 + m) * 128;
                const short* xrow = xb   + (size_t)((2 * Pn + tt) * 16 + m) * 128;
                #pragma unroll
                for (int c = 0; c < 4; c++) {
                    a[tt][c]     = *(const short8*)(arow + c * 32 + q * 8);
                    a[tt][c + 4] = *(const short8*)(xrow + c * 32 + q * 8);
                }
            }
        }
        // ---- phase 2: p = h@W2_l (waves 0,1), o = h@W2_r + b2 (waves 2,3)
        f32x4 acc2[2][2];
        #pragma unroll
        for (int tt = 0; tt < 2; tt++) {
            short8 a2[4];
            int rowbyte = (tt * 16 + m) * 256;
            #pragma unroll
            for (int c = 0; c < 4; c++)
                a2[c] = *(const short8*)(hb0 + rowbyte + ((q * 16 + c * 64) ^ rsw));
            #pragma unroll
            for (int t = 0; t < 2; t++) acc2[tt][t] = (f32x4){0.f, 0.f, 0.f, 0.f};
            #pragma unroll
            for (int c = 0; c < 4; c++)
                #pragma unroll
                for (int t = 0; t < 2; t++)
                    acc2[tt][t] = __builtin_amdgcn_mfma_f32_16x16x32_bf16(a2[c], w2[t][c], acc2[tt][t], 0, 0, 0);
        }
        if (wave < 2) {
            #pragma unroll
            for (int tt = 0; tt < 2; tt++)
                #pragma unroll
                for (int t = 0; t < 2; t++) {
                    int colc = pw * 32 + t * 16 + m;
                    #pragma unroll
                    for (int r = 0; r < 4; r++) {
                        int rr = (2 * P + tt) * 16 + q * 4 + r;
                        float pv = acc2[tt][t][r];
                        int w8 = __builtin_amdgcn_cvt_pk_fp8_f32(pv, pv, 0, false);
                        p8[(size_t)rr * 64 + colc] = (unsigned char)(w8 & 0xFF);
                    }
                }
        } else {
            #pragma unroll
            for (int tt = 0; tt < 2; tt++)
                #pragma unroll
                for (int t = 0; t < 2; t++) {
                    int colc = pw * 32 + t * 16 + m;
                    #pragma unroll
                    for (int r = 0; r < 4; r++) {
                        int rr = (2 * P + tt) * 16 + q * 4 + r;
                        out[(size_t)rr * 64 + colc] = acc2[tt][t][r] + bias2[t];
                    }
                }
        }
        if (Pn >= 3125) break;
        P = Pn;
        buf ^= 1;
    }
}

extern "C" void kernel_launch(void* const* d_in, const int* in_sizes, int n_in,
                              void* d_out, int out_size, void* d_ws, size_t ws_size,
                              hipStream_t stream) {
    const float* x    = (const float*)d_in[0];
    const int*   edge = (const int*)d_in[1];
    const float* W1_l = (const float*)d_in[2];
    const float* b1   = (const float*)d_in[3];
    const float* W1_r = (const float*)d_in[4];
    const float* W2_l = (const float*)d_in[5];
    const float* b2   = (const float*)d_in[6];
    const float* W2_r = (const float*)d_in[7];
    float* out = (float*)d_out;

    // ---- workspace layout (~86 MB) ----
    int* iw = (int*)d_ws;
    int* deg_i  = iw;                        // 100000
    int* cursor = iw + 100000;               // 100000 (row starts)
    int* bktcur = iw + 200000;               // 256 bucket cursors (zeroed below)
    float* inv_deg = (float*)(iw + 200256);  // 100096
    int* col    = iw + 300352;               // 196*9216 = 1806336 (gapped CSR)
    short* xb   = (short*)(iw + 2106688);    // 12.8M bf16
    short* hb   = xb + 12800000;             // 12.8M region: xq then p8/pq
    short* ag1  = hb + 12800000;             // 12.8M bf16 (layer-1 agg)
    short* W1t  = ag1 + 12800000;            // 32768
    short* W2lt = W1t + 32768;               // 8192
    short* W2rt = W2lt + 8192;               // 8192
    unsigned int* xq = (unsigned int*)hb;    // phaseA writes, agg128 reads, then dead
    int* pairs = (int*)ag1;                  // overlay: consumed by fill before agg128 writes ag1
    unsigned char* p8 = (unsigned char*)hb;  // overlay: xq dead after agg128
    unsigned int*  pq = (unsigned int*)hb;

    hipMemsetAsync(bktcur, 0, 256 * sizeof(int), stream);

    // phase A: single-pass bucket binning + bf16/fp8 prep, one grid
    phaseA_kernel<<<7224, 256, 0, stream>>>(edge, x, W1_l, W1_r, W2_l, W2_r,
                                            bktcur, pairs, xb, xq, W1t, W2lt, W2rt);
    // CSR build (per-bucket, fixed stride, one thread per node)
    fused_fill_kernel<<<NB, 512, 0, stream>>>(bktcur, pairs, deg_i, cursor, inv_deg, col);

    // layer 1 aggregation (16 lanes/node, 8-deep unroll)
    agg128_kernel<<<6250, 256, 0, stream>>>(cursor, deg_i, col, xq, inv_deg, ag1);
    // fused layer-1 GEMM + layer-2 projection (persistent, post-barrier prefetch)
    gemm12_mfma<<<512, 256, 0, stream>>>(ag1, xb, W1t, b1, W2lt, W2rt, b2, p8, out);
    // layer 2 aggregation (RMW on out, early RMW-read, 8-deep unroll)
    agg64_kernel<<<3125, 256, 0, stream>>>(cursor, deg_i, col, pq, inv_deg, out);
}

// Round 11
// 231.740 us; speedup vs baseline: 1.1423x; 1.0630x over previous
//
#include <hip/hip_runtime.h>

#define N_NODES   100000
#define N_EDGES   1600000
#define BSHIFT    9
#define NB        196        // ceil(100000 / 512)
#define BSTRIDE   9216       // per-bucket capacity: mean 8192, +11 sigma margin

typedef __attribute__((ext_vector_type(8))) short short8;
typedef __attribute__((ext_vector_type(4))) float f32x4;
typedef __attribute__((ext_vector_type(2))) float f32x2;

__device__ __forceinline__ unsigned short f2bf(float f) {
    unsigned u = __float_as_uint(f);
    u += 0x7FFF + ((u >> 16) & 1);          // round-to-nearest-even
    return (unsigned short)(u >> 16);
}

__device__ __forceinline__ int load_src(const int* e, int is64, int i) {
    return is64 ? e[2 * i] : e[i];
}
__device__ __forceinline__ int load_dst(const int* e, int is64, int i) {
    return is64 ? e[2 * (N_EDGES + i)] : e[N_EDGES + i];
}

// In-block edge-width self-detect: for int64 data all odd 32-bit words of the
// first 1024 entries are 0; for int32 they're random indices.
__device__ __forceinline__ int block_detect_is64(const int* e, int* s_nz) {
    if (threadIdx.x == 0) *s_nz = 0;
    __syncthreads();
    int v = 0;
    for (int i = threadIdx.x; i < 1024; i += 256) v |= e[2 * i + 1];
    if (v) atomicOr(s_nz, 1);
    __syncthreads();
    return (*s_nz == 0) ? 1 : 0;
}

// ---------------- phase A: single-pass bucket-binning + bf16/fp8 prep ------
// pairs entry: src (17 bits) | local-dst (9 bits) << 17.
__global__ __launch_bounds__(256) void phaseA_kernel(
        const int* __restrict__ e, const float* __restrict__ x,
        const float* __restrict__ W1_l, const float* __restrict__ W1_r,
        const float* __restrict__ W2_l, const float* __restrict__ W2_r,
        int* __restrict__ bktcur, int* __restrict__ pairs,
        short* __restrict__ xb, unsigned int* __restrict__ xq,
        short* __restrict__ W1t, short* __restrict__ W2lt, short* __restrict__ W2rt) {
    __shared__ int2 s_pairs[4096];
    __shared__ int s_cnt[256], s_off[256], s_base[256], s_cur[256];
    __shared__ int s_nz;
    const int blk = blockIdx.x;
    if (blk < 391) {
        const int tid = threadIdx.x;
        s_cnt[tid] = 0;
        int is64 = block_detect_is64(e, &s_nz);   // includes the needed barrier
        __syncthreads();
        int i0 = blk * 4096;
        int n = min(4096, N_EDGES - i0);
        int ls[16], ld[16];
        #pragma unroll
        for (int t = 0; t < 16; t++) {
            int k = t * 256 + tid;
            if (k < n) {
                ls[t] = load_src(e, is64, i0 + k);
                ld[t] = load_dst(e, is64, i0 + k);
                atomicAdd(&s_cnt[ld[t] >> BSHIFT], 1);
            }
        }
        __syncthreads();
        int lv = s_cnt[tid];
        s_off[tid] = lv;
        __syncthreads();
        for (int off = 1; off < 256; off <<= 1) {
            int t = (tid >= off) ? s_off[tid - off] : 0;
            __syncthreads();
            s_off[tid] += t;
            __syncthreads();
        }
        int excl = s_off[tid] - lv;
        int gb = 0;
        if (tid < NB && lv > 0) gb = atomicAdd(&bktcur[tid], lv);
        s_off[tid] = excl;
        s_base[tid] = tid * BSTRIDE + gb;
        s_cur[tid] = excl;
        __syncthreads();
        #pragma unroll
        for (int t = 0; t < 16; t++) {
            int k = t * 256 + tid;
            if (k < n) {
                int pos = atomicAdd(&s_cur[ld[t] >> BSHIFT], 1);
                s_pairs[pos] = (int2){ls[t], ld[t]};
            }
        }
        __syncthreads();
        for (int j = tid; j < n; j += 256) {
            int2 pr = s_pairs[j];
            int b = pr.y >> BSHIFT;
            pairs[s_base[b] + (j - s_off[b])] = pr.x | ((pr.y & 511) << 17);
        }
    } else if (blk < 6641) {
        int t = (blk - 391) * 256 + threadIdx.x;
        size_t i = (size_t)t * 8;
        float4 v0 = *(const float4*)&x[i];
        float4 v1 = *(const float4*)&x[i + 4];
        short8 o;
        o[0] = (short)f2bf(v0.x); o[1] = (short)f2bf(v0.y);
        o[2] = (short)f2bf(v0.z); o[3] = (short)f2bf(v0.w);
        o[4] = (short)f2bf(v1.x); o[5] = (short)f2bf(v1.y);
        o[6] = (short)f2bf(v1.z); o[7] = (short)f2bf(v1.w);
        *(short8*)&xb[i] = o;
        int w0 = __builtin_amdgcn_cvt_pk_fp8_f32(v0.x, v0.y, 0, false);
        w0 = __builtin_amdgcn_cvt_pk_fp8_f32(v0.z, v0.w, w0, true);
        int w1 = __builtin_amdgcn_cvt_pk_fp8_f32(v1.x, v1.y, 0, false);
        w1 = __builtin_amdgcn_cvt_pk_fp8_f32(v1.z, v1.w, w1, true);
        uint2 wq; wq.x = (unsigned int)w0; wq.y = (unsigned int)w1;
        *(uint2*)&xq[t * 2] = wq;
    } else {
        int i = (blk - 6641) * 256 + threadIdx.x;
        if (i < 32768) {
            int n = i >> 8, k = i & 255;
            float v = (k < 128) ? W1_l[k * 128 + n] : W1_r[(k - 128) * 128 + n];
            W1t[i] = (short)f2bf(v);
        } else if (i < 40960) {
            int j = i - 32768, n = j >> 7, k = j & 127;
            W2lt[j] = (short)f2bf(W2_l[k * 64 + n]);
        } else {
            int j = i - 40960, n = j >> 7, k = j & 127;
            W2rt[j] = (short)f2bf(W2_r[k * 64 + n]);
        }
    }
}

// ---------------- fused CSR tail (fixed-stride buckets, 512 thr/node) ------
__global__ __launch_bounds__(512) void fused_fill_kernel(
        const int* __restrict__ bktcur, const int* __restrict__ pairs,
        int* __restrict__ deg_i, int* __restrict__ cursor,
        float* __restrict__ inv_deg, int* __restrict__ col) {
    __shared__ int ldeg[512];
    __shared__ int ssum[512];
    const int tid = threadIdx.x;
    const int b = blockIdx.x;
    const int nbase = b << BSHIFT;
    ldeg[tid] = 0;
    __syncthreads();
    const int cnt = bktcur[b];
    const int p0 = b * BSTRIDE;
    for (int j = tid; j < cnt; j += 512)
        atomicAdd(&ldeg[pairs[p0 + j] >> 17], 1);
    __syncthreads();
    int d = ldeg[tid];
    ssum[tid] = d;
    __syncthreads();
    for (int off = 1; off < 512; off <<= 1) {
        int t = (tid >= off) ? ssum[tid - off] : 0;
        __syncthreads();
        ssum[tid] += t;
        __syncthreads();
    }
    int s = p0 + ssum[tid] - d;          // row start for node nbase+tid
    int node = nbase + tid;
    if (node < N_NODES) {
        deg_i[node] = d;
        cursor[node] = s;
        inv_deg[node] = 1.0f / fmaxf((float)d, 1.0f);
    }
    ldeg[tid] = s;                        // becomes scatter cursor
    __syncthreads();
    for (int j = tid; j < cnt; j += 512) {
        int pk = pairs[p0 + j];
        int pos = atomicAdd(&ldeg[pk >> 17], 1);
        col[pos] = pk & 0x1FFFF;
    }
}

// ---------------- fp8 helpers ----------------
__device__ __forceinline__ void acc_fp8x8(float* acc, uint2 w) {
    f32x2 f;
    f = __builtin_amdgcn_cvt_pk_f32_fp8((int)w.x, false); acc[0] += f[0]; acc[1] += f[1];
    f = __builtin_amdgcn_cvt_pk_f32_fp8((int)w.x, true);  acc[2] += f[0]; acc[3] += f[1];
    f = __builtin_amdgcn_cvt_pk_f32_fp8((int)w.y, false); acc[4] += f[0]; acc[5] += f[1];
    f = __builtin_amdgcn_cvt_pk_f32_fp8((int)w.y, true);  acc[6] += f[0]; acc[7] += f[1];
}

// layer-1 aggregation: fp8 rows (128 B), 16 lanes x 8 B per node.
// 8-deep batched main loop + MASKED final batch: the old scalar remainder
// loop cost ~deg%8 serial load latencies per node (in-order issue); the
// masked batch keeps full MLP on the tail. Clamped indices stay in-bounds;
// accumulation predicated on j<rem keeps the sum bit-identical.
__global__ __launch_bounds__(256) void agg128_kernel(
        const int* __restrict__ cursor, const int* __restrict__ deg_i,
        const int* __restrict__ col, const unsigned int* __restrict__ xq,
        const float* __restrict__ inv_deg, short* __restrict__ agg) {
    int node = blockIdx.x * 16 + (threadIdx.x >> 4);
    int lane = threadIdx.x & 15;
    int cnt = deg_i[node];
    int start = cursor[node];
    float acc[8] = {0.f};
    int k = 0;
    for (; k + 8 <= cnt; k += 8) {
        int s[8];
        #pragma unroll
        for (int j = 0; j < 8; j++) s[j] = col[start + k + j];
        uint2 w[8];
        #pragma unroll
        for (int j = 0; j < 8; j++)
            w[j] = *(const uint2*)(xq + (size_t)s[j] * 32 + lane * 2);
        #pragma unroll
        for (int j = 0; j < 8; j++) acc_fp8x8(acc, w[j]);
    }
    int rem = cnt - k;
    if (rem > 0) {
        int s[8];
        #pragma unroll
        for (int j = 0; j < 8; j++) s[j] = col[start + k + min(j, rem - 1)];
        uint2 w[8];
        #pragma unroll
        for (int j = 0; j < 8; j++)
            w[j] = *(const uint2*)(xq + (size_t)s[j] * 32 + lane * 2);
        #pragma unroll
        for (int j = 0; j < 8; j++)
            if (j < rem) acc_fp8x8(acc, w[j]);
    }
    float sc = inv_deg[node];
    short8 o;
    #pragma unroll
    for (int j = 0; j < 8; j++) o[j] = (short)f2bf(acc[j] * sc);
    *(short8*)(agg + (size_t)node * 128 + lane * 8) = o;
}

// layer-2 aggregation: fp8 p rows (64 B), 8 lanes x 8 B per node; RMW on
// out with the read issued BEFORE the gather; masked final batch (as above).
__global__ __launch_bounds__(256) void agg64_kernel(
        const int* __restrict__ cursor, const int* __restrict__ deg_i,
        const int* __restrict__ col, const unsigned int* __restrict__ pq,
        const float* __restrict__ inv_deg, float* __restrict__ out) {
    int node = blockIdx.x * 32 + (threadIdx.x >> 3);
    int lane = threadIdx.x & 7;
    int cnt = deg_i[node];
    int start = cursor[node];
    float sc = inv_deg[node];
    float* dst = out + (size_t)node * 64 + lane * 8;
    float4 r0 = *(float4*)dst;            // issue RMW reads early
    float4 r1 = *(float4*)(dst + 4);
    float acc[8] = {0.f};
    int k = 0;
    for (; k + 8 <= cnt; k += 8) {
        int s[8];
        #pragma unroll
        for (int j = 0; j < 8; j++) s[j] = col[start + k + j];
        uint2 w[8];
        #pragma unroll
        for (int j = 0; j < 8; j++)
            w[j] = *(const uint2*)(pq + (size_t)s[j] * 16 + lane * 2);
        #pragma unroll
        for (int j = 0; j < 8; j++) acc_fp8x8(acc, w[j]);
    }
    int rem = cnt - k;
    if (rem > 0) {
        int s[8];
        #pragma unroll
        for (int j = 0; j < 8; j++) s[j] = col[start + k + min(j, rem - 1)];
        uint2 w[8];
        #pragma unroll
        for (int j = 0; j < 8; j++)
            w[j] = *(const uint2*)(pq + (size_t)s[j] * 16 + lane * 2);
        #pragma unroll
        for (int j = 0; j < 8; j++)
            if (j < rem) acc_fp8x8(acc, w[j]);
    }
    r0.x += acc[0] * sc; r0.y += acc[1] * sc; r0.z += acc[2] * sc; r0.w += acc[3] * sc;
    r1.x += acc[4] * sc; r1.y += acc[5] * sc; r1.z += acc[6] * sc; r1.w += acc[7] * sc;
    *(float4*)dst = r0;
    *(float4*)(dst + 4) = r1;
}

// ---------------- fused persistent MFMA: h = relu(A@W1+b1) in LDS,
// then p8 = fp8(h@W2_l), out = h@W2_r + b2 — h never touches global.
// Exact R3/R7-measured configuration: 512 blocks, stride 512, VGPR 116.
__global__ __launch_bounds__(256, 2) void gemm12_mfma(
        const short* __restrict__ agg1, const short* __restrict__ xb,
        const short* __restrict__ W1t, const float* __restrict__ b1,
        const short* __restrict__ W2lt, const short* __restrict__ W2rt,
        const float* __restrict__ b2,
        unsigned char* __restrict__ p8, float* __restrict__ out) {
    __shared__ __align__(16) char hs[2][8192];   // 2 x 32 rows x 256 B, XOR-swizzled
    const int wave = threadIdx.x >> 6, lane = threadIdx.x & 63;
    const int m = lane & 15, q = lane >> 4;

    // phase-1 W1 fragments: this wave's 32 h-cols [wave*32, wave*32+32)
    short8 breg[2][8];
    #pragma unroll
    for (int t = 0; t < 2; t++)
        #pragma unroll
        for (int c = 0; c < 8; c++)
            breg[t][c] = *(const short8*)(W1t + (size_t)(wave * 32 + t * 16 + m) * 256 + c * 32 + q * 8);
    float bias1[2];
    bias1[0] = b1[wave * 32 + m];
    bias1[1] = b1[wave * 32 + 16 + m];

    // phase-2 fragments: waves 0,1 -> p cols [pw*32,+32); waves 2,3 -> out cols
    const int pw = wave & 1;
    const short* Wp = (wave < 2) ? W2lt : W2rt;
    short8 w2[2][4];
    #pragma unroll
    for (int t = 0; t < 2; t++)
        #pragma unroll
        for (int c = 0; c < 4; c++)
            w2[t][c] = *(const short8*)(Wp + (size_t)(pw * 32 + t * 16 + m) * 128 + c * 32 + q * 8);
    float bias2[2];
    bias2[0] = b2[pw * 32 + m];
    bias2[1] = b2[pw * 32 + 16 + m];

    int P = blockIdx.x;                      // pair index: tiles 2P, 2P+1
    short8 a[2][8];
    #pragma unroll
    for (int tt = 0; tt < 2; tt++) {
        const short* arow = agg1 + (size_t)((2 * P + tt) * 16 + m) * 128;
        const short* xrow = xb   + (size_t)((2 * P + tt) * 16 + m) * 128;
        #pragma unroll
        for (int c = 0; c < 4; c++) {
            a[tt][c]     = *(const short8*)(arow + c * 32 + q * 8);
            a[tt][c + 4] = *(const short8*)(xrow + c * 32 + q * 8);
        }
    }
    const int wb = wave * 64 + m * 2;        // phase-1 write col byte base
    const int rsw = (m & 7) << 4;            // phase-2 read swizzle
    int buf = 0;
    while (true) {
        // ---- phase 1: h = relu(A @ W1 + b1), 2 tiles x this wave's 32 cols
        f32x4 acc[2][2];
        #pragma unroll
        for (int tt = 0; tt < 2; tt++)
            #pragma unroll
            for (int t = 0; t < 2; t++) acc[tt][t] = (f32x4){0.f, 0.f, 0.f, 0.f};
        #pragma unroll
        for (int c = 0; c < 8; c++)
            #pragma unroll
            for (int tt = 0; tt < 2; tt++)
                #pragma unroll
                for (int t = 0; t < 2; t++)
                    acc[tt][t] = __builtin_amdgcn_mfma_f32_16x16x32_bf16(a[tt][c], breg[t][c], acc[tt][t], 0, 0, 0);
        // issue next pair's A-loads now (loads stay in flight across phase 2)
        int Pn = P + 512;
        if (Pn < 3125) {
            #pragma unroll
            for (int tt = 0; tt < 2; tt++) {
                const short* arow = agg1 + (size_t)((2 * Pn + tt) * 16 + m) * 128;
                const short* xrow = xb   + (size_t)((2 * Pn + tt) * 16 + m) * 128;
                #pragma unroll
                for (int c = 0; c < 4; c++) {
                    a[tt][c]     = *(const short8*)(arow + c * 32 + q * 8);
                    a[tt][c + 4] = *(const short8*)(xrow + c * 32 + q * 8);
                }
            }
        }
        // write h tile to swizzled LDS
        char* hb0 = hs[buf];
        #pragma unroll
        for (int tt = 0; tt < 2; tt++)
            #pragma unroll
            for (int t = 0; t < 2; t++)
                #pragma unroll
                for (int r = 0; r < 4; r++) {
                    int row = tt * 16 + q * 4 + r;
                    int byteoff = row * 256 + ((wb + t * 32) ^ ((row & 7) << 4));
                    float v = fmaxf(acc[tt][t][r] + bias1[t], 0.f);
                    *(short*)(hb0 + byteoff) = (short)f2bf(v);
                }
        __syncthreads();
        // ---- phase 2: p = h@W2_l (waves 0,1), o = h@W2_r + b2 (waves 2,3)
        f32x4 acc2[2][2];
        #pragma unroll
        for (int tt = 0; tt < 2; tt++) {
            short8 a2[4];
            int rowbyte = (tt * 16 + m) * 256;
            #pragma unroll
            for (int c = 0; c < 4; c++)
                a2[c] = *(const short8*)(hb0 + rowbyte + ((q * 16 + c * 64) ^ rsw));
            #pragma unroll
            for (int t = 0; t < 2; t++) acc2[tt][t] = (f32x4){0.f, 0.f, 0.f, 0.f};
            #pragma unroll
            for (int c = 0; c < 4; c++)
                #pragma unroll
                for (int t = 0; t < 2; t++)
                    acc2[tt][t] = __builtin_amdgcn_mfma_f32_16x16x32_bf16(a2[c], w2[t][c], acc2[tt][t], 0, 0, 0);
        }
        if (wave < 2) {
            #pragma unroll
            for (int tt = 0; tt < 2; tt++)
                #pragma unroll
                for (int t = 0; t < 2; t++) {
                    int colc = pw * 32 + t * 16 + m;
                    #pragma unroll
                    for (int r = 0; r < 4; r++) {
                        int rr = (2 * P + tt) * 16 + q * 4 + r;
                        float pv = acc2[tt][t][r];
                        int w8 = __builtin_amdgcn_cvt_pk_fp8_f32(pv, pv, 0, false);
                        p8[(size_t)rr * 64 + colc] = (unsigned char)(w8 & 0xFF);
                    }
                }
        } else {
            #pragma unroll
            for (int tt = 0; tt < 2; tt++)
                #pragma unroll
                for (int t = 0; t < 2; t++) {
                    int colc = pw * 32 + t * 16 + m;
                    #pragma unroll
                    for (int r = 0; r < 4; r++) {
                        int rr = (2 * P + tt) * 16 + q * 4 + r;
                        out[(size_t)rr * 64 + colc] = acc2[tt][t][r] + bias2[t];
                    }
                }
        }
        if (Pn >= 3125) break;
        P = Pn;
        buf ^= 1;
    }
}

extern "C" void kernel_launch(void* const* d_in, const int* in_sizes, int n_in,
                              void* d_out, int out_size, void* d_ws, size_t ws_size,
                              hipStream_t stream) {
    const float* x    = (const float*)d_in[0];
    const int*   edge = (const int*)d_in[1];
    const float* W1_l = (const float*)d_in[2];
    const float* b1   = (const float*)d_in[3];
    const float* W1_r = (const float*)d_in[4];
    const float* W2_l = (const float*)d_in[5];
    const float* b2   = (const float*)d_in[6];
    const float* W2_r = (const float*)d_in[7];
    float* out = (float*)d_out;

    // ---- workspace layout (~86 MB) ----
    int* iw = (int*)d_ws;
    int* deg_i  = iw;                        // 100000
    int* cursor = iw + 100000;               // 100000 (row starts)
    int* bktcur = iw + 200000;               // 256 bucket cursors (zeroed below)
    float* inv_deg = (float*)(iw + 200256);  // 100096
    int* col    = iw + 300352;               // 196*9216 = 1806336 (gapped CSR)
    short* xb   = (short*)(iw + 2106688);    // 12.8M bf16
    short* hb   = xb + 12800000;             // 12.8M region: xq then p8/pq
    short* ag1  = hb + 12800000;             // 12.8M bf16 (layer-1 agg)
    short* W1t  = ag1 + 12800000;            // 32768
    short* W2lt = W1t + 32768;               // 8192
    short* W2rt = W2lt + 8192;               // 8192
    unsigned int* xq = (unsigned int*)hb;    // phaseA writes, agg128 reads, then dead
    int* pairs = (int*)ag1;                  // overlay: consumed by fill before agg128 writes ag1
    unsigned char* p8 = (unsigned char*)hb;  // overlay: xq dead after agg128
    unsigned int*  pq = (unsigned int*)hb;

    hipMemsetAsync(bktcur, 0, 256 * sizeof(int), stream);

    // phase A: single-pass bucket binning + bf16/fp8 prep, one grid
    phaseA_kernel<<<6833, 256, 0, stream>>>(edge, x, W1_l, W1_r, W2_l, W2_r,
                                            bktcur, pairs, xb, xq, W1t, W2lt, W2rt);
    // CSR build (per-bucket, fixed stride, one thread per node)
    fused_fill_kernel<<<NB, 512, 0, stream>>>(bktcur, pairs, deg_i, cursor, inv_deg, col);

    // layer 1 aggregation (16 lanes/node, 8-deep unroll + masked tail)
    agg128_kernel<<<6250, 256, 0, stream>>>(cursor, deg_i, col, xq, inv_deg, ag1);
    // fused layer-1 GEMM + layer-2 projection (persistent, R3/R7 config)
    gemm12_mfma<<<512, 256, 0, stream>>>(ag1, xb, W1t, b1, W2lt, W2rt, b2, p8, out);
    // layer 2 aggregation (RMW on out, early RMW-read, masked tail)
    agg64_kernel<<<3125, 256, 0, stream>>>(cursor, deg_i, col, pq, inv_deg, out);
}